// Round 7
// baseline (263.023 us; speedup 1.0000x reference)
//
#include <hip/hip_runtime.h>
#include <hip/hip_fp16.h>

#define DIM 128
#define NPB 128        // nodes per bucket
#define BCAP 2560      // bucket capacity (mean 2046, +11 sigma)
#define T_SCAT 2048

typedef _Float16 half8 __attribute__((ext_vector_type(8)));
typedef float floatx4 __attribute__((ext_vector_type(4)));
typedef float floatx2 __attribute__((ext_vector_type(2)));

// ============ bscatter (single-pass, 8 edges/thread in regs) + folded prep ============
// bucket b = dst >> 7. Bucket b owns slots [b*BCAP, (b+1)*BCAP) in be and csr.
__global__ __launch_bounds__(256) void bscatter_prep_k(
        const int* __restrict__ ei, int E, int ntiles,
        int2* __restrict__ be, int* __restrict__ bcur,
        const float* __restrict__ W1, const float* __restrict__ W2,
        const float* __restrict__ Wo, const float* __restrict__ b2,
        const float* __restrict__ bo,
        __half* __restrict__ w1frag, float* __restrict__ w2o,
        float* __restrict__ cbuf) {
    if (blockIdx.x >= (unsigned)ntiles) {
        // ---- prep tail blocks ----
        int bid = blockIdx.x - ntiles;
        if (bid < 8) {
            int idx = bid * 256 + threadIdx.x;   // 0..2047
            int ct = idx >> 8, ks = (idx >> 6) & 3, l = idx & 63;
            int m = l & 15, q = l >> 4;
            half8 vals;
#pragma unroll
            for (int j = 0; j < 8; j++)
                vals[j] = (_Float16)W1[(ks * 32 + q * 8 + j) * DIM + ct * 16 + m];
            ((half8*)w1frag)[idx] = vals;
        } else {
            int t = threadIdx.x;
            if (t < 128) {
                float s = 0.f;
                for (int k = 0; k < 128; k++) s += W2[t * 128 + k] * Wo[k];
                w2o[t] = s;
            }
            if (t == 0) {
                float c = bo[0];
                for (int k = 0; k < 128; k++) c += b2[k] * Wo[k];
                cbuf[0] = c;
            }
        }
        return;
    }
    __shared__ int lcnt[1024];
    __shared__ int lscan[1024];
    __shared__ int lbase[1024];
    __shared__ int wsum[4];
    __shared__ int2 stage[T_SCAT];
    const int t = threadIdx.x;
    const int lane = t & 63, w = t >> 6;
    const int tile0 = blockIdx.x * T_SCAT;
    int tcnt = E - tile0; if (tcnt > T_SCAT) tcnt = T_SCAT;
    for (int i = t; i < 1024; i += 256) lcnt[i] = 0;
    __syncthreads();
    // phase 1: load 8 edges into regs, rank via LDS atomic
    int es[8], ed[8], er[8];
#pragma unroll
    for (int j = 0; j < 8; j++) {
        int li = j * 256 + t;
        ed[j] = -1;
        if (li < tcnt) {
            es[j] = ei[tile0 + li];
            ed[j] = ei[E + tile0 + li];
            er[j] = atomicAdd(&lcnt[ed[j] >> 7], 1);
        }
    }
    __syncthreads();
    // phase 2: scan 1024 counts (4/thread, shfl wave-scan), reserve global space
    const int b4 = t * 4;
    int c0 = lcnt[b4], c1 = lcnt[b4 + 1], c2 = lcnt[b4 + 2], c3 = lcnt[b4 + 3];
    int s4 = c0 + c1 + c2 + c3;
    int v = s4;
#pragma unroll
    for (int off = 1; off < 64; off <<= 1) {
        int u = __shfl_up(v, off, 64);
        if (lane >= off) v += u;
    }
    if (lane == 63) wsum[w] = v;
    __syncthreads();
    int wbase = 0;
#pragma unroll
    for (int i = 0; i < 4; i++) wbase += (i < w) ? wsum[i] : 0;
    int run = wbase + v - s4;
    lscan[b4] = run;
    if (c0) lbase[b4] = b4 * BCAP + atomicAdd(&bcur[b4], c0);
    run += c0; lscan[b4 + 1] = run;
    if (c1) lbase[b4 + 1] = (b4 + 1) * BCAP + atomicAdd(&bcur[b4 + 1], c1);
    run += c1; lscan[b4 + 2] = run;
    if (c2) lbase[b4 + 2] = (b4 + 2) * BCAP + atomicAdd(&bcur[b4 + 2], c2);
    run += c2; lscan[b4 + 3] = run;
    if (c3) lbase[b4 + 3] = (b4 + 3) * BCAP + atomicAdd(&bcur[b4 + 3], c3);
    __syncthreads();
    // phase 3: stage from regs
#pragma unroll
    for (int j = 0; j < 8; j++)
        if (ed[j] >= 0) stage[lscan[ed[j] >> 7] + er[j]] = make_int2(es[j], ed[j]);
    __syncthreads();
    // phase 4: contiguous-run copy out
    for (int i = t; i < tcnt; i += 256) {
        int2 edg = stage[i];
        int b = edg.y >> 7;
        be[lbase[b] + (i - lscan[b])] = edg;
    }
}

// ============ bsort: single-pass counting sort per 128-node bucket ============
#define BK 10   // ceil(BCAP/256)
__global__ __launch_bounds__(256) void bsort_k(const int2* __restrict__ be,
                                               const int* __restrict__ bcur,
                                               int* __restrict__ csr,
                                               int* __restrict__ rp,
                                               int* __restrict__ re,
                                               float* __restrict__ dinv,
                                               int N) {
    __shared__ int lcnt[NPB];
    __shared__ int lscan[NPB];
    __shared__ int wsum2[2];
    __shared__ int stage[BCAP];
    const int t = threadIdx.x;
    const int b = blockIdx.x;
    const int s = b * BCAP;
    const int cnt = bcur[b];
    if (t < NPB) lcnt[t] = 0;
    __syncthreads();
    // phase 1: load + rank in regs (constant-indexed unroll -> registers)
    int src_r[BK], meta_r[BK];
#pragma unroll
    for (int k = 0; k < BK; k++) {
        int i = t + k * 256;
        meta_r[k] = -1;
        if (i < cnt) {
            int2 e = be[s + i];
            int d = e.y & (NPB - 1);
            int r = atomicAdd(&lcnt[d], 1);
            src_r[k] = e.x;
            meta_r[k] = d | (r << 8);
        }
    }
    __syncthreads();
    // phase 2: scan 128 counters (threads 0..127, shfl within wave + wave combine)
    int v = 0, iv = 0;
    if (t < NPB) {
        v = lcnt[t];
        iv = v;
#pragma unroll
        for (int off = 1; off < 64; off <<= 1) {
            int u = __shfl_up(iv, off, 64);
            if ((t & 63) >= off) iv += u;
        }
        if ((t & 63) == 63) wsum2[t >> 6] = iv;
    }
    __syncthreads();
    if (t < NPB) {
        int wbase = (t >= 64) ? wsum2[0] : 0;
        int excl = wbase + iv - v;
        lscan[t] = excl;
        int node = b * NPB + t;
        if (node < N) {
            rp[node] = s + excl;
            re[node] = s + excl + v;
            dinv[node] = rsqrtf((float)v + 1.0f);
        }
    }
    __syncthreads();
    // phase 3: stage sorted srcs
#pragma unroll
    for (int k = 0; k < BK; k++) {
        if (meta_r[k] >= 0) {
            int d = meta_r[k] & 255;
            int r = meta_r[k] >> 8;
            stage[lscan[d] + r] = src_r[k];
        }
    }
    __syncthreads();
    // phase 4: coalesced write-out
    for (int i = t; i < cnt; i += 256) csr[s + i] = stage[i];
}

// ---------------- MFMA GEMM: A[N x 128](fp8 e4m3) = X @ W1 ----------------
__global__ __launch_bounds__(256) void gemm2_k(const float* __restrict__ X,
                                               const __half* __restrict__ w1frag,
                                               unsigned char* __restrict__ A, int N) {
    const int t = threadIdx.x;
    const int w = t >> 6, l = t & 63;
    const int q = l >> 4;
    const int node = blockIdx.x * 64 + w * 16 + (l & 15);
    const bool valid = node < N;
    half8 bfrag[4];
#pragma unroll
    for (int ks = 0; ks < 4; ks++) {
        float4 f0 = make_float4(0, 0, 0, 0), f1 = make_float4(0, 0, 0, 0);
        if (valid) {
            const float* px = X + (size_t)node * DIM + ks * 32 + q * 8;
            f0 = *(const float4*)px;
            f1 = *(const float4*)(px + 4);
        }
        bfrag[ks][0] = (_Float16)f0.x; bfrag[ks][1] = (_Float16)f0.y;
        bfrag[ks][2] = (_Float16)f0.z; bfrag[ks][3] = (_Float16)f0.w;
        bfrag[ks][4] = (_Float16)f1.x; bfrag[ks][5] = (_Float16)f1.y;
        bfrag[ks][6] = (_Float16)f1.z; bfrag[ks][7] = (_Float16)f1.w;
    }
    const half8* wf = (const half8*)w1frag;
#pragma unroll
    for (int ct = 0; ct < 8; ct++) {
        floatx4 acc = {0.f, 0.f, 0.f, 0.f};
#pragma unroll
        for (int ks = 0; ks < 4; ks++) {
            half8 afrag = wf[(ct * 4 + ks) * 64 + l];
            acc = __builtin_amdgcn_mfma_f32_16x16x32_f16(afrag, bfrag[ks], acc, 0, 0, 0);
        }
        if (valid) {
            int st = 0;
            st = __builtin_amdgcn_cvt_pk_fp8_f32(acc[0], acc[1], st, false);
            st = __builtin_amdgcn_cvt_pk_fp8_f32(acc[2], acc[3], st, true);
            *(int*)(A + (size_t)node * DIM + ct * 16 + q * 4) = st;
        }
    }
}

__device__ __forceinline__ void dec8(int2 r, float* f) {
    floatx2 a = __builtin_amdgcn_cvt_pk_f32_fp8(r.x, false);
    floatx2 b = __builtin_amdgcn_cvt_pk_f32_fp8(r.x, true);
    floatx2 c = __builtin_amdgcn_cvt_pk_f32_fp8(r.y, false);
    floatx2 d = __builtin_amdgcn_cvt_pk_f32_fp8(r.y, true);
    f[0] = a[0]; f[1] = a[1]; f[2] = b[0]; f[3] = b[1];
    f[4] = c[0]; f[5] = c[1]; f[6] = d[0]; f[7] = d[1];
}

// ---------------- layer-1 aggregation (fp8 gathers), fused epilogue -> z ----------
__global__ __launch_bounds__(256) void agg1_k(const unsigned char* __restrict__ A,
                                              const int* __restrict__ rp,
                                              const int* __restrict__ re,
                                              const int* __restrict__ csr_src,
                                              const float* __restrict__ dinv,
                                              const float* __restrict__ b1,
                                              const float* __restrict__ w2o,
                                              float* __restrict__ z, int N) {
    const int li = threadIdx.x & 31;
    const int node = blockIdx.x * 8 + (threadIdx.x >> 5);
    if (node >= N) return;
    const int eoff = (li & 15) * 8;
    const float dn = dinv[node];
    const int s0 = rp[node], s1 = re[node];
    float acc[8];
    {
        int2 raw = *(const int2*)(A + (size_t)node * DIM + eoff);
        float hv[8]; dec8(raw, hv);
        float w0 = (li < 16) ? dn * dn : 0.f;
#pragma unroll
        for (int e = 0; e < 8; e++) acc[e] = hv[e] * w0;
    }
    for (int base = s0; base < s1; base += 32) {
        int sidx = 0; float dsl = 0.f;
        if (base + li < s1) { sidx = csr_src[base + li]; dsl = dinv[sidx]; }
        int nloc = s1 - base; if (nloc > 32) nloc = 32;
        int npair = (nloc + 1) >> 1;
#pragma unroll 2
        for (int j = 0; j < npair; j++) {
            int sel = 2 * j + (li >> 4);
            int ssrc = __shfl(sidx, sel, 32);
            float wgt = __shfl(dsl, sel, 32) * dn;
            int2 hraw = *(const int2*)(A + (size_t)ssrc * DIM + eoff);
            float h[8]; dec8(hraw, h);
#pragma unroll
            for (int e = 0; e < 8; e++) acc[e] = fmaf(h[e], wgt, acc[e]);
        }
    }
#pragma unroll
    for (int e = 0; e < 8; e++) acc[e] += __shfl_xor(acc[e], 16, 32);
    float sum = 0.f;
    if (li < 16) {
        float4 b0 = *(const float4*)(b1 + eoff);
        float4 b3 = *(const float4*)(b1 + eoff + 4);
        float4 w0 = *(const float4*)(w2o + eoff);
        float4 w3 = *(const float4*)(w2o + eoff + 4);
        sum  = fmaxf(acc[0] + b0.x, 0.f) * w0.x;
        sum += fmaxf(acc[1] + b0.y, 0.f) * w0.y;
        sum += fmaxf(acc[2] + b0.z, 0.f) * w0.z;
        sum += fmaxf(acc[3] + b0.w, 0.f) * w0.w;
        sum += fmaxf(acc[4] + b3.x, 0.f) * w3.x;
        sum += fmaxf(acc[5] + b3.y, 0.f) * w3.y;
        sum += fmaxf(acc[6] + b3.z, 0.f) * w3.z;
        sum += fmaxf(acc[7] + b3.w, 0.f) * w3.w;
    }
#pragma unroll
    for (int off = 16; off > 0; off >>= 1) sum += __shfl_down(sum, off, 32);
    if (li == 0) z[node] = sum;
}

// ---------------- final: out[n] = dn*sum(dinv[s]*z[s]) + dn^2*z[n] + c ----------------
__global__ void final_k(const float* __restrict__ z, const float* __restrict__ dinv,
                        const int* __restrict__ rp, const int* __restrict__ re,
                        const int* __restrict__ csr_src,
                        const float* __restrict__ cbuf, float* __restrict__ out, int N) {
    int n = blockIdx.x * 256 + threadIdx.x;
    if (n >= N) return;
    float dn = dinv[n];
    int s0 = rp[n], s1 = re[n];
    float s = 0.f;
    for (int i = s0; i < s1; i++) {
        int sx = csr_src[i];
        s = fmaf(dinv[sx], z[sx], s);
    }
    out[n] = fmaf(dn, s, fmaf(dn * dn, z[n], cbuf[0]));
}

extern "C" void kernel_launch(void* const* d_in, const int* in_sizes, int n_in,
                              void* d_out, int out_size, void* d_ws, size_t ws_size,
                              hipStream_t stream) {
    const float* x  = (const float*)d_in[0];
    const int*   ei = (const int*)d_in[1];
    const float* W1 = (const float*)d_in[2];
    const float* b1 = (const float*)d_in[3];
    const float* W2 = (const float*)d_in[4];
    const float* b2 = (const float*)d_in[5];
    const float* Wo = (const float*)d_in[6];
    const float* bo = (const float*)d_in[7];
    float* out = (float*)d_out;

    const int N = in_sizes[0] / DIM;
    const int E = in_sizes[1] / 2;
    const int NB = (N + NPB - 1) >> 7;         // 128-node buckets (<=1024)
    const int ntiles = (E + T_SCAT - 1) / T_SCAT;

    char* p = (char*)d_ws;
    auto alloc = [&](size_t bytes) {
        void* r = (void*)p;
        p += (bytes + 255) & ~size_t(255);
        return r;
    };
    // be (NB*BCAP*8 = 16 MB) aliases A (fp8, 12.8 MB): be dead before gemm2_k writes A.
    size_t asz = (size_t)N * DIM, besz = (size_t)NB * BCAP * 8;
    char* big     = (char*)alloc(asz > besz ? asz : besz);
    unsigned char* A = (unsigned char*)big;
    int2*  be     = (int2*)big;
    float* z      = (float*)alloc((size_t)N * 4);
    float* dinv   = (float*)alloc((size_t)N * 4);
    float* w2o    = (float*)alloc(128 * 4);
    float* cbuf   = (float*)alloc(16);
    __half* w1frag= (__half*)alloc(2048 * 8 * 2);   // 32 KB
    int* rp       = (int*)alloc((size_t)N * 4);
    int* re       = (int*)alloc((size_t)N * 4);
    int* csr      = (int*)alloc((size_t)NB * BCAP * 4);
    int* bcur     = (int*)alloc(1024 * 4);

    hipMemsetAsync(bcur, 0, (size_t)NB * 4, stream);

    bscatter_prep_k<<<ntiles + 9, 256, 0, stream>>>(ei, E, ntiles, be, bcur,
                                                    W1, W2, Wo, b2, bo,
                                                    w1frag, w2o, cbuf);
    bsort_k<<<NB, 256, 0, stream>>>(be, bcur, csr, rp, re, dinv, N);
    gemm2_k<<<(N + 63) / 64, 256, 0, stream>>>(x, w1frag, A, N);
    agg1_k<<<(N + 7) / 8, 256, 0, stream>>>(A, rp, re, csr, dinv, b1, w2o, z, N);
    final_k<<<(N + 255) / 256, 256, 0, stream>>>(z, dinv, rp, re, csr, cbuf, out, N);
}

// Round 8
// 232.226 us; speedup vs baseline: 1.1326x; 1.1326x over previous
//
#include <hip/hip_runtime.h>
#include <hip/hip_fp16.h>

#define DIM 128
#define NPB 256        // nodes per bucket
#define BCAP 5120      // bucket capacity (mean 4092, +16 sigma)
#define T_SCAT 4096

typedef _Float16 half8 __attribute__((ext_vector_type(8)));
typedef float floatx4 __attribute__((ext_vector_type(4)));
typedef float floatx2 __attribute__((ext_vector_type(2)));

// ---------------- shared gemm block body: 64 nodes -> A fp8 ----------------
__device__ __forceinline__ void gemm_block(const float* __restrict__ X,
                                           const __half* __restrict__ w1frag,
                                           unsigned char* __restrict__ A,
                                           int N, int gb) {
    const int t = threadIdx.x;
    const int w = t >> 6, l = t & 63;
    const int q = l >> 4;
    const int node = gb * 64 + w * 16 + (l & 15);
    const bool valid = node < N;
    half8 bfrag[4];
#pragma unroll
    for (int ks = 0; ks < 4; ks++) {
        float4 f0 = make_float4(0, 0, 0, 0), f1 = make_float4(0, 0, 0, 0);
        if (valid) {
            const float* px = X + (size_t)node * DIM + ks * 32 + q * 8;
            f0 = *(const float4*)px;
            f1 = *(const float4*)(px + 4);
        }
        bfrag[ks][0] = (_Float16)f0.x; bfrag[ks][1] = (_Float16)f0.y;
        bfrag[ks][2] = (_Float16)f0.z; bfrag[ks][3] = (_Float16)f0.w;
        bfrag[ks][4] = (_Float16)f1.x; bfrag[ks][5] = (_Float16)f1.y;
        bfrag[ks][6] = (_Float16)f1.z; bfrag[ks][7] = (_Float16)f1.w;
    }
    const half8* wf = (const half8*)w1frag;
#pragma unroll
    for (int ct = 0; ct < 8; ct++) {
        floatx4 acc = {0.f, 0.f, 0.f, 0.f};
#pragma unroll
        for (int ks = 0; ks < 4; ks++) {
            half8 afrag = wf[(ct * 4 + ks) * 64 + l];
            acc = __builtin_amdgcn_mfma_f32_16x16x32_f16(afrag, bfrag[ks], acc, 0, 0, 0);
        }
        if (valid) {
            int st = 0;
            st = __builtin_amdgcn_cvt_pk_fp8_f32(acc[0], acc[1], st, false);
            st = __builtin_amdgcn_cvt_pk_fp8_f32(acc[2], acc[3], st, true);
            *(int*)(A + (size_t)node * DIM + ct * 16 + q * 4) = st;
        }
    }
}

// ---------------- L1 prep: w1frag, w2o, cbuf, zero bcur ----------------
__global__ void prep_k(const float* __restrict__ W1, const float* __restrict__ W2,
                       const float* __restrict__ Wo, const float* __restrict__ b2,
                       const float* __restrict__ bo,
                       __half* __restrict__ w1frag, float* __restrict__ w2o,
                       float* __restrict__ cbuf, int* __restrict__ bcur) {
    if (blockIdx.x < 8) {
        int idx = blockIdx.x * 256 + threadIdx.x;   // 0..2047
        int ct = idx >> 8, ks = (idx >> 6) & 3, l = idx & 63;
        int m = l & 15, q = l >> 4;
        half8 vals;
#pragma unroll
        for (int j = 0; j < 8; j++)
            vals[j] = (_Float16)W1[(ks * 32 + q * 8 + j) * DIM + ct * 16 + m];
        ((half8*)w1frag)[idx] = vals;
    } else if (blockIdx.x == 8) {
        int t = threadIdx.x;
        if (t < 128) {
            float s = 0.f;
            for (int k = 0; k < 128; k++) s += W2[t * 128 + k] * Wo[k];
            w2o[t] = s;
        }
        if (t == 0) {
            float c = bo[0];
            for (int k = 0; k < 128; k++) c += b2[k] * Wo[k];
            cbuf[0] = c;
        }
    } else {
#pragma unroll
        for (int i = 0; i < 4; i++) bcur[threadIdx.x + i * 256] = 0;
    }
}

// ---------------- L2: bscatter (R6 two-pass) + gemm half 1 ----------------
// bucket b = dst >> 8; bucket b owns [b*BCAP, (b+1)*BCAP) in be and csr.
__global__ __launch_bounds__(256) void scatter_gemm_k(
        const int* __restrict__ ei, int E, int ntiles,
        int2* __restrict__ be, int* __restrict__ bcur,
        const float* __restrict__ X, const __half* __restrict__ w1frag,
        unsigned char* __restrict__ A, int N) {
    if (blockIdx.x >= (unsigned)ntiles) {
        gemm_block(X, w1frag, A, N, blockIdx.x - ntiles);
        return;
    }
    __shared__ int lcnt[1024];
    __shared__ int lscan[1024];
    __shared__ int lbase[1024];
    __shared__ int wsum[4];
    __shared__ int2 stage[T_SCAT];
    const int t = threadIdx.x;
    const int lane = t & 63, w = t >> 6;
    const int tile0 = blockIdx.x * T_SCAT;
    int tcnt = E - tile0; if (tcnt > T_SCAT) tcnt = T_SCAT;
    for (int i = t; i < 1024; i += 256) lcnt[i] = 0;
    __syncthreads();
    // pass A: histogram
    for (int i = t; i < tcnt; i += 256)
        atomicAdd(&lcnt[ei[E + tile0 + i] >> 8], 1);
    __syncthreads();
    // scan 1024 counts (4/thread, shfl wave-scan, 1 barrier); reserve global space
    const int b4 = t * 4;
    int c0 = lcnt[b4], c1 = lcnt[b4 + 1], c2 = lcnt[b4 + 2], c3 = lcnt[b4 + 3];
    int s4 = c0 + c1 + c2 + c3;
    int v = s4;
#pragma unroll
    for (int off = 1; off < 64; off <<= 1) {
        int u = __shfl_up(v, off, 64);
        if (lane >= off) v += u;
    }
    if (lane == 63) wsum[w] = v;
    __syncthreads();
    int wbase = 0;
#pragma unroll
    for (int i = 0; i < 4; i++) wbase += (i < w) ? wsum[i] : 0;
    int run = wbase + v - s4;
    lscan[b4] = run;
    if (c0) lbase[b4] = b4 * BCAP + atomicAdd(&bcur[b4], c0);
    run += c0; lscan[b4 + 1] = run;
    if (c1) lbase[b4 + 1] = (b4 + 1) * BCAP + atomicAdd(&bcur[b4 + 1], c1);
    run += c1; lscan[b4 + 2] = run;
    if (c2) lbase[b4 + 2] = (b4 + 2) * BCAP + atomicAdd(&bcur[b4 + 2], c2);
    run += c2; lscan[b4 + 3] = run;
    if (c3) lbase[b4 + 3] = (b4 + 3) * BCAP + atomicAdd(&bcur[b4 + 3], c3);
    lcnt[b4] = 0; lcnt[b4 + 1] = 0; lcnt[b4 + 2] = 0; lcnt[b4 + 3] = 0;
    __syncthreads();
    // pass B: re-read (L2-hot), rank, stage
    for (int i = t; i < tcnt; i += 256) {
        int s = ei[tile0 + i];
        int d = ei[E + tile0 + i];
        int b = d >> 8;
        int r = atomicAdd(&lcnt[b], 1);
        stage[lscan[b] + r] = make_int2(s, d);
    }
    __syncthreads();
    // contiguous-run copy out (~10.5-edge runs)
    for (int i = t; i < tcnt; i += 256) {
        int2 ed = stage[i];
        int b = ed.y >> 8;
        be[lbase[b] + (i - lscan[b])] = ed;
    }
}

// ---------------- L3: bsort (R6 two-pass) + gemm half 2 ----------------
__global__ __launch_bounds__(256) void sort_gemm_k(
        const int2* __restrict__ be, const int* __restrict__ bcur,
        int* __restrict__ csr, int* __restrict__ rp, int* __restrict__ re,
        float* __restrict__ dinv, int N, int nb,
        const float* __restrict__ X, const __half* __restrict__ w1frag,
        unsigned char* __restrict__ A, int gemmBase) {
    if (blockIdx.x >= (unsigned)nb) {
        gemm_block(X, w1frag, A, N, gemmBase + blockIdx.x - nb);
        return;
    }
    __shared__ int lcnt[256];
    __shared__ int lscan[256];
    __shared__ int lc2[256];
    __shared__ int wsum[4];
    __shared__ int stage[BCAP];
    const int t = threadIdx.x;
    const int lane = t & 63, w = t >> 6;
    const int b = blockIdx.x;
    const int s = b * BCAP;
    int cnt = bcur[b]; if (cnt > BCAP) cnt = BCAP;
    lcnt[t] = 0; lc2[t] = 0;
    __syncthreads();
    for (int i = t; i < cnt; i += 256)
        atomicAdd(&lcnt[be[s + i].y & 255], 1);
    __syncthreads();
    int v = lcnt[t];
    int iv = v;
#pragma unroll
    for (int off = 1; off < 64; off <<= 1) {
        int u = __shfl_up(iv, off, 64);
        if (lane >= off) iv += u;
    }
    if (lane == 63) wsum[w] = iv;
    __syncthreads();
    int wbase = 0;
#pragma unroll
    for (int i = 0; i < 4; i++) wbase += (i < w) ? wsum[i] : 0;
    int excl = wbase + iv - v;
    lscan[t] = excl;
    int node = b * NPB + t;
    if (node < N) {
        rp[node] = s + excl;
        re[node] = s + excl + v;
        dinv[node] = rsqrtf((float)v + 1.0f);
    }
    __syncthreads();
    for (int i = t; i < cnt; i += 256) {
        int2 ed = be[s + i];
        int d = ed.y & 255;
        int r = atomicAdd(&lc2[d], 1);
        stage[lscan[d] + r] = ed.x;
    }
    __syncthreads();
    for (int i = t; i < cnt; i += 256) csr[s + i] = stage[i];
}

__device__ __forceinline__ void dec8(int2 r, float* f) {
    floatx2 a = __builtin_amdgcn_cvt_pk_f32_fp8(r.x, false);
    floatx2 b = __builtin_amdgcn_cvt_pk_f32_fp8(r.x, true);
    floatx2 c = __builtin_amdgcn_cvt_pk_f32_fp8(r.y, false);
    floatx2 d = __builtin_amdgcn_cvt_pk_f32_fp8(r.y, true);
    f[0] = a[0]; f[1] = a[1]; f[2] = b[0]; f[3] = b[1];
    f[4] = c[0]; f[5] = c[1]; f[6] = d[0]; f[7] = d[1];
}

// ---------------- layer-1 aggregation (fp8 gathers), fused epilogue -> z ----------
__global__ __launch_bounds__(256) void agg1_k(const unsigned char* __restrict__ A,
                                              const int* __restrict__ rp,
                                              const int* __restrict__ re,
                                              const int* __restrict__ csr_src,
                                              const float* __restrict__ dinv,
                                              const float* __restrict__ b1,
                                              const float* __restrict__ w2o,
                                              float* __restrict__ z, int N) {
    const int li = threadIdx.x & 31;
    const int node = blockIdx.x * 8 + (threadIdx.x >> 5);
    if (node >= N) return;
    const int eoff = (li & 15) * 8;
    const float dn = dinv[node];
    const int s0 = rp[node], s1 = re[node];
    float acc[8];
    {
        int2 raw = *(const int2*)(A + (size_t)node * DIM + eoff);
        float hv[8]; dec8(raw, hv);
        float w0 = (li < 16) ? dn * dn : 0.f;
#pragma unroll
        for (int e = 0; e < 8; e++) acc[e] = hv[e] * w0;
    }
    for (int base = s0; base < s1; base += 32) {
        int sidx = 0; float dsl = 0.f;
        if (base + li < s1) { sidx = csr_src[base + li]; dsl = dinv[sidx]; }
        int nloc = s1 - base; if (nloc > 32) nloc = 32;
        int npair = (nloc + 1) >> 1;
#pragma unroll 2
        for (int j = 0; j < npair; j++) {
            int sel = 2 * j + (li >> 4);
            int ssrc = __shfl(sidx, sel, 32);
            float wgt = __shfl(dsl, sel, 32) * dn;
            int2 hraw = *(const int2*)(A + (size_t)ssrc * DIM + eoff);
            float h[8]; dec8(hraw, h);
#pragma unroll
            for (int e = 0; e < 8; e++) acc[e] = fmaf(h[e], wgt, acc[e]);
        }
    }
#pragma unroll
    for (int e = 0; e < 8; e++) acc[e] += __shfl_xor(acc[e], 16, 32);
    float sum = 0.f;
    if (li < 16) {
        float4 b0 = *(const float4*)(b1 + eoff);
        float4 b3 = *(const float4*)(b1 + eoff + 4);
        float4 w0 = *(const float4*)(w2o + eoff);
        float4 w3 = *(const float4*)(w2o + eoff + 4);
        sum  = fmaxf(acc[0] + b0.x, 0.f) * w0.x;
        sum += fmaxf(acc[1] + b0.y, 0.f) * w0.y;
        sum += fmaxf(acc[2] + b0.z, 0.f) * w0.z;
        sum += fmaxf(acc[3] + b0.w, 0.f) * w0.w;
        sum += fmaxf(acc[4] + b3.x, 0.f) * w3.x;
        sum += fmaxf(acc[5] + b3.y, 0.f) * w3.y;
        sum += fmaxf(acc[6] + b3.z, 0.f) * w3.z;
        sum += fmaxf(acc[7] + b3.w, 0.f) * w3.w;
    }
#pragma unroll
    for (int off = 16; off > 0; off >>= 1) sum += __shfl_down(sum, off, 32);
    if (li == 0) z[node] = sum;
}

// ---------------- final: out[n] = dn*sum(dinv[s]*z[s]) + dn^2*z[n] + c ----------------
__global__ void final_k(const float* __restrict__ z, const float* __restrict__ dinv,
                        const int* __restrict__ rp, const int* __restrict__ re,
                        const int* __restrict__ csr_src,
                        const float* __restrict__ cbuf, float* __restrict__ out, int N) {
    int n = blockIdx.x * 256 + threadIdx.x;
    if (n >= N) return;
    float dn = dinv[n];
    int s0 = rp[n], s1 = re[n];
    float s = 0.f;
    for (int i = s0; i < s1; i++) {
        int sx = csr_src[i];
        s = fmaf(dinv[sx], z[sx], s);
    }
    out[n] = fmaf(dn, s, fmaf(dn * dn, z[n], cbuf[0]));
}

extern "C" void kernel_launch(void* const* d_in, const int* in_sizes, int n_in,
                              void* d_out, int out_size, void* d_ws, size_t ws_size,
                              hipStream_t stream) {
    const float* x  = (const float*)d_in[0];
    const int*   ei = (const int*)d_in[1];
    const float* W1 = (const float*)d_in[2];
    const float* b1 = (const float*)d_in[3];
    const float* W2 = (const float*)d_in[4];
    const float* b2 = (const float*)d_in[5];
    const float* Wo = (const float*)d_in[6];
    const float* bo = (const float*)d_in[7];
    float* out = (float*)d_out;

    const int N = in_sizes[0] / DIM;
    const int E = in_sizes[1] / 2;
    const int NB = (N + NPB - 1) >> 8;         // 256-node buckets
    const int ntiles = (E + T_SCAT - 1) / T_SCAT;
    const int ngemm = (N + 63) / 64;
    const int g1 = ngemm / 2;                  // gemm blocks in L2
    const int g2 = ngemm - g1;                 // gemm blocks in L3

    char* p = (char*)d_ws;
    auto alloc = [&](size_t bytes) {
        void* r = (void*)p;
        p += (bytes + 255) & ~size_t(255);
        return r;
    };
    // A and be are now SEPARATE (both live during L2/L3 overlap).
    unsigned char* A = (unsigned char*)alloc((size_t)N * DIM);          // 12.8 MB
    int2*  be     = (int2*)alloc((size_t)NB * BCAP * 8);                // 16 MB
    int*   csr    = (int*)alloc((size_t)NB * BCAP * 4);                 // 8 MB
    float* z      = (float*)alloc((size_t)N * 4);
    float* dinv   = (float*)alloc((size_t)N * 4);
    float* w2o    = (float*)alloc(128 * 4);
    float* cbuf   = (float*)alloc(16);
    __half* w1frag= (__half*)alloc(2048 * 8 * 2);   // 32 KB
    int* rp       = (int*)alloc((size_t)N * 4);
    int* re       = (int*)alloc((size_t)N * 4);
    int* bcur     = (int*)alloc(1024 * 4);

    prep_k<<<10, 256, 0, stream>>>(W1, W2, Wo, b2, bo, w1frag, w2o, cbuf, bcur);
    scatter_gemm_k<<<ntiles + g1, 256, 0, stream>>>(ei, E, ntiles, be, bcur,
                                                    x, w1frag, A, N);
    sort_gemm_k<<<NB + g2, 256, 0, stream>>>(be, bcur, csr, rp, re, dinv, N, NB,
                                             x, w1frag, A, g1);
    agg1_k<<<(N + 7) / 8, 256, 0, stream>>>(A, rp, re, csr, dinv, b1, w2o, z, N);
    final_k<<<(N + 255) / 256, 256, 0, stream>>>(z, dinv, rp, re, csr, cbuf, out, N);
}